// Round 8
// baseline (263.336 us; speedup 1.0000x reference)
//
#include <hip/hip_runtime.h>
#include <stdint.h>

typedef __attribute__((ext_vector_type(8))) short bf16x8;
typedef __attribute__((ext_vector_type(4))) float f32x4;

static constexpr int O1_ELEMS   = 512*3*3*128*128;    // 75497472 floats
static constexpr int NTILES     = 4608;               // 512*9 tiles of 128x128 f32
static constexpr int HEAD_TILES = 64;                 // 64*64KB = 4MB = wb2 scratch
static constexpr int NCOMP      = 24;                 // m-tiles of 64 rows
static constexpr int NSTREAM    = 2272;               // (4608-64)/2272 = 2 tiles/blk

__device__ inline unsigned short f32_to_bf16(float f) {
    union { float f; uint32_t u; } v; v.f = f;
    uint32_t r = v.u + 0x7FFF + ((v.u >> 16) & 1);    // RNE
    return (unsigned short)(r >> 16);
}

__device__ inline bf16x8 bf16x8_from_f32(const float* p) {
    float4 v0 = *(const float4*)p;
    float4 v1 = *(const float4*)(p + 4);
    union { bf16x8 v; unsigned short s[8]; } u;
    u.s[0] = f32_to_bf16(v0.x); u.s[1] = f32_to_bf16(v0.y);
    u.s[2] = f32_to_bf16(v0.z); u.s[3] = f32_to_bf16(v0.w);
    u.s[4] = f32_to_bf16(v1.x); u.s[5] = f32_to_bf16(v1.y);
    u.s[6] = f32_to_bf16(v1.z); u.s[7] = f32_to_bf16(v1.w);
    return u.v;
}

// write one 128x128 out1 tile (512 threads): out1[tile] = x[n,i,:] ⊗ y[n,j,:]
__device__ inline void write_tile(int tile, const float* __restrict__ x,
                                  const f32x4* __restrict__ y4,
                                  f32x4* __restrict__ o4, int t) {
    const int b4 = t & 31, a0 = t >> 5;               // b4: f4 col, a0: row 0..15
    int n  = tile / 9;
    int ij = tile - n * 9;
    int i  = ij / 3, j = ij - i * 3;
    f32x4 yv = y4[(n * 3 + j) * 32 + b4];             // held in reg for 8 passes
    const float* xrow = x + (n * 3 + i) * 128;
    f32x4* dst = o4 + (size_t)tile * 4096 + a0 * 32 + b4;
    #pragma unroll
    for (int p = 0; p < 8; ++p) {
        float xs = xrow[p * 16 + a0];                 // 2-address wave broadcast
        f32x4 r = yv * xs;
        *dst = r;                                     // plain store (L2 aggregates)
        dst += 512;                                   // 16 rows * 32 f4
    }
}

// ---- conv: wb2[a][k][b] = bf16(w[a][b][k]) (wb2 lives at out1 head) ----
__global__ __launch_bounds__(256) void conv_kernel(const float* __restrict__ w,
                                                   unsigned short* __restrict__ wb2) {
    __shared__ unsigned short lt[128][132];
    const int a = blockIdx.x;
    const int t = threadIdx.x;
    const float4* src = (const float4*)(w + (size_t)a * 16384);
    #pragma unroll
    for (int it = 0; it < 16; ++it) {                  // 4096 float4 = 128x128 f32
        int fidx = it * 256 + t;
        float4 v = src[fidx];
        int b = fidx >> 5, k4 = fidx & 31;
        unsigned short* d = &lt[b][k4 * 4];
        d[0] = f32_to_bf16(v.x); d[1] = f32_to_bf16(v.y);
        d[2] = f32_to_bf16(v.z); d[3] = f32_to_bf16(v.w);
    }
    __syncthreads();
    const int k = t >> 1, bh = t & 1;
    uint4* dst = (uint4*)(wb2 + (size_t)a * 16384 + (size_t)k * 128 + bh * 64);
    #pragma unroll
    for (int i8 = 0; i8 < 8; ++i8) {
        uint32_t pk[4];
        #pragma unroll
        for (int q = 0; q < 4; ++q) {
            uint32_t lo = lt[bh * 64 + i8 * 8 + q * 2][k];
            uint32_t hi = lt[bh * 64 + i8 * 8 + q * 2 + 1][k];
            pk[q] = lo | (hi << 16);
        }
        uint4 vv = {pk[0], pk[1], pk[2], pk[3]};
        dst[i8] = vv;
    }
}

// ---- mega: [0,NCOMP) fused out2 (m-tile 64, full k, all a); rest stream out1 --
__global__ __launch_bounds__(512, 2) void mega_kernel(const float* __restrict__ x,
                                                      const float* __restrict__ y,
                                                      const float* __restrict__ a_s,
                                                      const unsigned short* __restrict__ wb2,
                                                      float* __restrict__ out1,
                                                      float* __restrict__ out2) {
    if ((int)blockIdx.x >= NCOMP) {
        const int sb = (int)blockIdx.x - NCOMP;
        const f32x4* y4 = (const f32x4*)y;
        f32x4* o4 = (f32x4*)out1;
        for (int tile = HEAD_TILES + sb; tile < NTILES; tile += NSTREAM)
            write_tile(tile, x, y4, o4, (int)threadIdx.x);
        return;
    }

    // compute block mt: out2 rows [mt*64, +64), all 128 k, all 128 a.
    // 8 waves: wm = wave>>2 (m-half), wk = wave&3 (k-quarter).
    __shared__ float xsh[32][3][64];       // [ac][i][m']  24 KB, per 32-a chunk
    const int mt  = blockIdx.x;            // 0..23
    const int tid = threadIdx.x;
    const int l   = tid & 63;
    const int wv  = tid >> 6;
    const int wm  = wv >> 2, wk = wv & 3;
    const int l15 = l & 15, lg = l >> 4;

    // A-frags (Y, bf16 cvt in-reg): row m = mt*64+wm*32+mf*16+l15, b = ks*32+lg*8..
    bf16x8 afrag[2][4];
    #pragma unroll
    for (int mf = 0; mf < 2; ++mf)
        #pragma unroll
        for (int ks = 0; ks < 4; ++ks)
            afrag[mf][ks] = bf16x8_from_f32(
                y + (size_t)(mt * 64 + wm * 32 + mf * 16 + l15) * 128 + ks * 32 + lg * 8);

    float acc2[3][2][2][4] = {};
    // B-frag base: k' = wk*32 + kf*16 + l15 (col), elems b = ks*32 + lg*8..
    const unsigned short* wbase = wb2 + (size_t)(wk * 32 + l15) * 128 + lg * 8;

    for (int seg = 0; seg < 4; ++seg) {
        __syncthreads();
        // x tile for this 32-a chunk: 32a x 3i x 64m = 6144 floats
        #pragma unroll
        for (int p = 0; p < 12; ++p) {
            int e = tid + p * 512;
            int ac = e / 192, r = e - ac * 192, i = r >> 6, mm = r & 63;
            int n = (mt * 64 + mm) / 3;
            xsh[ac][i][mm] = x[n * 384 + i * 128 + seg * 32 + ac];
        }
        __syncthreads();

        #pragma unroll 2
        for (int ac = 0; ac < 32; ++ac) {
            const int a = seg * 32 + ac;
            const unsigned short* wp = wbase + (size_t)a * 16384;
            bf16x8 bf[2][4];
            #pragma unroll
            for (int kf = 0; kf < 2; ++kf)
                #pragma unroll
                for (int ks = 0; ks < 4; ++ks)
                    bf[kf][ks] = *(const bf16x8*)(wp + kf * 2048 + ks * 32);

            f32x4 tt[2][2] = {{{0.f,0.f,0.f,0.f},{0.f,0.f,0.f,0.f}},
                              {{0.f,0.f,0.f,0.f},{0.f,0.f,0.f,0.f}}};
            #pragma unroll
            for (int ks = 0; ks < 4; ++ks)
                #pragma unroll
                for (int mf = 0; mf < 2; ++mf)
                    #pragma unroll
                    for (int kf = 0; kf < 2; ++kf)
                        tt[mf][kf] = __builtin_amdgcn_mfma_f32_16x16x32_bf16(
                            afrag[mf][ks], bf[kf][ks], tt[mf][kf], 0, 0, 0);

            #pragma unroll
            for (int i = 0; i < 3; ++i) {
                #pragma unroll
                for (int mf = 0; mf < 2; ++mf) {
                    float4 xv = *(const float4*)&xsh[ac][i][wm * 32 + mf * 16 + lg * 4];
                    #pragma unroll
                    for (int kf = 0; kf < 2; ++kf) {
                        acc2[i][mf][kf][0] += xv.x * tt[mf][kf][0];
                        acc2[i][mf][kf][1] += xv.y * tt[mf][kf][1];
                        acc2[i][mf][kf][2] += xv.z * tt[mf][kf][2];
                        acc2[i][mf][kf][3] += xv.w * tt[mf][kf][3];
                    }
                }
            }
        }
    }

    const float alpha = 0.75f * a_s[0];
    #pragma unroll
    for (int i = 0; i < 3; ++i)
        #pragma unroll
        for (int mf = 0; mf < 2; ++mf)
            #pragma unroll
            for (int kf = 0; kf < 2; ++kf) {
                const int kcol = wk * 32 + kf * 16 + l15;
                #pragma unroll
                for (int r = 0; r < 4; ++r) {
                    int m = mt * 64 + wm * 32 + mf * 16 + lg * 4 + r;
                    int n = m / 3, j = m - 3 * n;
                    out2[((size_t)(n * 3 + i) * 3 + j) * 128 + kcol] =
                        alpha * acc2[i][mf][kf][r];
                }
            }
}

// ---- finish: rewrite out1 head (the wb2 scratch region = tiles 0..63) ----
__global__ __launch_bounds__(512) void finish_kernel(const float* __restrict__ x,
                                                     const float* __restrict__ y,
                                                     float* __restrict__ out1) {
    write_tile((int)blockIdx.x, x, (const f32x4*)y, (f32x4*)out1, (int)threadIdx.x);
}

extern "C" void kernel_launch(void* const* d_in, const int* in_sizes, int n_in,
                              void* d_out, int out_size, void* d_ws, size_t ws_size,
                              hipStream_t stream) {
    const float* w  = (const float*)d_in[0];
    const float* as = (const float*)d_in[1];
    const float* x  = (const float*)d_in[2];
    const float* y  = (const float*)d_in[3];
    float* out1 = (float*)d_out;
    float* out2 = out1 + O1_ELEMS;

    // wb2 scratch at out1 head (rewritten by finish): no ws dependency
    unsigned short* wb2 = (unsigned short*)out1;

    conv_kernel<<<128, 256, 0, stream>>>(w, wb2);
    mega_kernel<<<NCOMP + NSTREAM, 512, 0, stream>>>(x, y, as, wb2, out1, out2);
    finish_kernel<<<HEAD_TILES, 512, 0, stream>>>(x, y, out1);
}

// Round 9
// 104.756 us; speedup vs baseline: 2.5138x; 2.5138x over previous
//
#include <hip/hip_runtime.h>
#include <stdint.h>

typedef __attribute__((ext_vector_type(8))) short bf16x8;
typedef __attribute__((ext_vector_type(4))) float f32x4;

static constexpr int O1_ELEMS    = 512*3*3*128*128;   // 75497472 floats
static constexpr int WB2_FLOATS  = 1048576;           // 4 MB bf16 wb2[a][k][b]
static constexpr int P_FLOATS    = 512*9*128;         // 589824 per partial slice
static constexpr int NSEG        = 8;                 // a-split
static constexpr int SKIP_FLOATS = WB2_FLOATS + NSEG*P_FLOATS;  // 5767168
static constexpr int SKIP4       = SKIP_FLOATS / 4;   // 1441792 float4
static constexpr int TOTAL4      = O1_ELEMS / 4;      // 18874368

__device__ inline unsigned short f32_to_bf16(float f) {
    union { float f; uint32_t u; } v; v.f = f;
    uint32_t r = v.u + 0x7FFF + ((v.u >> 16) & 1);    // RNE
    return (unsigned short)(r >> 16);
}

__device__ inline bf16x8 bf16x8_from_f32(const float* p) {
    float4 v0 = *(const float4*)p;
    float4 v1 = *(const float4*)(p + 4);
    union { bf16x8 v; unsigned short s[8]; } u;
    u.s[0] = f32_to_bf16(v0.x); u.s[1] = f32_to_bf16(v0.y);
    u.s[2] = f32_to_bf16(v0.z); u.s[3] = f32_to_bf16(v0.w);
    u.s[4] = f32_to_bf16(v1.x); u.s[5] = f32_to_bf16(v1.y);
    u.s[6] = f32_to_bf16(v1.z); u.s[7] = f32_to_bf16(v1.w);
    return u.v;
}

// out1[n,i,j,a,b] = x[n,i,a]*y[n,j,b], flat float4 range [lo, hi)
__device__ inline void out1_range(int lo, int hi, int stride, int start,
                                  const float* __restrict__ x,
                                  const float4* __restrict__ y4,
                                  float4* __restrict__ o4) {
    for (int idx = lo + start; idx < hi; idx += stride) {
        int n   = idx / 36864;
        int rem = idx - n * 36864;
        int ij  = rem >> 12;
        int r2  = rem & 4095;
        int aa  = r2 >> 5;
        int b4  = r2 & 31;
        int i = ij / 3, j = ij - 3 * i;
        float  xs1 = x[(n * 3 + i) * 128 + aa];
        float4 yv  = y4[(n * 3 + j) * 32 + b4];
        float4 r; r.x = xs1 * yv.x; r.y = xs1 * yv.y; r.z = xs1 * yv.z; r.w = xs1 * yv.w;
        o4[idx] = r;
    }
}

// ---- conv: wb2[a][k][b] = bf16(w[a][b][k]) (wb2 lives at out1 head) ----
__global__ __launch_bounds__(256) void conv_kernel(const float* __restrict__ w,
                                                   unsigned short* __restrict__ wb2) {
    __shared__ unsigned short lt[128][132];
    const int a = blockIdx.x;
    const int t = threadIdx.x;
    const float4* src = (const float4*)(w + (size_t)a * 16384);
    #pragma unroll
    for (int it = 0; it < 16; ++it) {                  // 4096 float4 = 128x128 f32
        int fidx = it * 256 + t;
        float4 v = src[fidx];
        int b = fidx >> 5, k4 = fidx & 31;
        unsigned short* d = &lt[b][k4 * 4];
        d[0] = f32_to_bf16(v.x); d[1] = f32_to_bf16(v.y);
        d[2] = f32_to_bf16(v.z); d[3] = f32_to_bf16(v.w);
    }
    __syncthreads();
    const int k = t >> 1, bh = t & 1;
    uint4* dst = (uint4*)(wb2 + (size_t)a * 16384 + (size_t)k * 128 + bh * 64);
    #pragma unroll
    for (int i8 = 0; i8 < 8; ++i8) {
        uint32_t pk[4];
        #pragma unroll
        for (int q = 0; q < 4; ++q) {
            uint32_t lo = lt[bh * 64 + i8 * 8 + q * 2][k];
            uint32_t hi = lt[bh * 64 + i8 * 8 + q * 2 + 1][k];
            pk[q] = lo | (hi << 16);
        }
        uint4 vv = {pk[0], pk[1], pk[2], pk[3]};
        dst[i8] = vv;
    }
}

// ---- comp: partial[aseg][m,k] = sum_{a in seg} x[n,i,a] * t_a[m,k] ----
// grid 768 = 48 mt x 2 kt x 8 aseg, 256 threads
__global__ __launch_bounds__(256) void comp_kernel(const float* __restrict__ x,
                                                   const float* __restrict__ y,
                                                   const unsigned short* __restrict__ wb2,
                                                   float* __restrict__ partial) {
    __shared__ float xsh[16][3][32];       // [ac][i][m']  6 KB
    const int bid  = blockIdx.x;
    const int aseg = bid & 7;
    const int kt   = (bid >> 3) & 1;
    const int mt   = bid >> 4;             // 0..47
    const int tid  = threadIdx.x;
    const int l    = tid & 63;
    const int wv   = tid >> 6;             // wave -> k-cols [wv*16, +16) of kt half
    const int l15  = l & 15, lg = l >> 4;

    // A-frags (Y, bf16 cvt in-reg)
    bf16x8 afrag[2][4];
    #pragma unroll
    for (int Mt = 0; Mt < 2; ++Mt)
        #pragma unroll
        for (int ks = 0; ks < 4; ++ks)
            afrag[Mt][ks] = bf16x8_from_f32(
                y + (size_t)(mt * 32 + Mt * 16 + l15) * 128 + ks * 32 + lg * 8);

    // x tile: 16a x 3i x 32m = 1536 floats
    #pragma unroll
    for (int p = 0; p < 6; ++p) {
        int e = tid + p * 256;
        int ac = e / 96, r = e - ac * 96, i = r >> 5, mm = r & 31;
        int n = (mt * 32 + mm) / 3;
        xsh[ac][i][mm] = x[n * 384 + i * 128 + aseg * 16 + ac];
    }
    __syncthreads();

    float acc2[3][2][4] = {};
    const unsigned short* wbase =
        wb2 + (size_t)(kt * 64 + wv * 16 + l15) * 128 + lg * 8;

    #pragma unroll 2
    for (int ac = 0; ac < 16; ++ac) {
        const int a = aseg * 16 + ac;
        const unsigned short* wp = wbase + (size_t)a * 16384;
        bf16x8 bf0 = *(const bf16x8*)(wp);
        bf16x8 bf1 = *(const bf16x8*)(wp + 32);
        bf16x8 bf2 = *(const bf16x8*)(wp + 64);
        bf16x8 bf3 = *(const bf16x8*)(wp + 96);

        f32x4 t0 = {0.f, 0.f, 0.f, 0.f}, t1 = {0.f, 0.f, 0.f, 0.f};
        t0 = __builtin_amdgcn_mfma_f32_16x16x32_bf16(afrag[0][0], bf0, t0, 0, 0, 0);
        t1 = __builtin_amdgcn_mfma_f32_16x16x32_bf16(afrag[1][0], bf0, t1, 0, 0, 0);
        t0 = __builtin_amdgcn_mfma_f32_16x16x32_bf16(afrag[0][1], bf1, t0, 0, 0, 0);
        t1 = __builtin_amdgcn_mfma_f32_16x16x32_bf16(afrag[1][1], bf1, t1, 0, 0, 0);
        t0 = __builtin_amdgcn_mfma_f32_16x16x32_bf16(afrag[0][2], bf2, t0, 0, 0, 0);
        t1 = __builtin_amdgcn_mfma_f32_16x16x32_bf16(afrag[1][2], bf2, t1, 0, 0, 0);
        t0 = __builtin_amdgcn_mfma_f32_16x16x32_bf16(afrag[0][3], bf3, t0, 0, 0, 0);
        t1 = __builtin_amdgcn_mfma_f32_16x16x32_bf16(afrag[1][3], bf3, t1, 0, 0, 0);

        #pragma unroll
        for (int i = 0; i < 3; ++i) {
            float4 xv0 = *(const float4*)&xsh[ac][i][lg * 4];
            float4 xv1 = *(const float4*)&xsh[ac][i][16 + lg * 4];
            acc2[i][0][0] += xv0.x * t0[0]; acc2[i][0][1] += xv0.y * t0[1];
            acc2[i][0][2] += xv0.z * t0[2]; acc2[i][0][3] += xv0.w * t0[3];
            acc2[i][1][0] += xv1.x * t1[0]; acc2[i][1][1] += xv1.y * t1[1];
            acc2[i][1][2] += xv1.z * t1[2]; acc2[i][1][3] += xv1.w * t1[3];
        }
    }

    float* pp = partial + (size_t)aseg * P_FLOATS;
    const int kcol = kt * 64 + wv * 16 + l15;
    #pragma unroll
    for (int i = 0; i < 3; ++i)
        #pragma unroll
        for (int Mt = 0; Mt < 2; ++Mt)
            #pragma unroll
            for (int r = 0; r < 4; ++r) {
                int m = mt * 32 + Mt * 16 + lg * 4 + r;
                int n = m / 3, j = m - 3 * n;
                pp[((size_t)(n * 3 + i) * 3 + j) * 128 + kcol] = acc2[i][Mt][r];
            }
}

// ---- reduce: out2 = alpha * sum over 8 partial slices (coalesced) ----
__global__ __launch_bounds__(256) void reduce_kernel(const float* __restrict__ a_s,
                                                     const float* __restrict__ partial,
                                                     float* __restrict__ out2) {
    const int e = (int)blockIdx.x * 256 + (int)threadIdx.x;   // grid 2304 exact
    float s = 0.f;
    #pragma unroll
    for (int sg = 0; sg < NSEG; ++sg) s += partial[(size_t)sg * P_FLOATS + e];
    out2[e] = 0.75f * a_s[0] * s;
}

// ---- stream: out1 tail [SKIP4, TOTAL4) ----
__global__ __launch_bounds__(256) void stream_kernel(const float* __restrict__ x,
                                                     const float* __restrict__ y,
                                                     float* __restrict__ out1) {
    out1_range(SKIP4, TOTAL4, 4096 * 256,
               (int)blockIdx.x * 256 + (int)threadIdx.x,
               x, (const float4*)y, (float4*)out1);
}

// ---- finish: rewrite scratch head [0, SKIP4) with true out1 ----
__global__ __launch_bounds__(256) void finish_kernel(const float* __restrict__ x,
                                                     const float* __restrict__ y,
                                                     float* __restrict__ out1) {
    out1_range(0, SKIP4, 1408 * 256,
               (int)blockIdx.x * 256 + (int)threadIdx.x,
               x, (const float4*)y, (float4*)out1);
}

extern "C" void kernel_launch(void* const* d_in, const int* in_sizes, int n_in,
                              void* d_out, int out_size, void* d_ws, size_t ws_size,
                              hipStream_t stream) {
    const float* w  = (const float*)d_in[0];
    const float* as = (const float*)d_in[1];
    const float* x  = (const float*)d_in[2];
    const float* y  = (const float*)d_in[3];
    float* out1 = (float*)d_out;
    float* out2 = out1 + O1_ELEMS;

    // scratch at out1 head: wb2 (4 MB) + 8 partial slices (18 MB); rewritten by finish
    unsigned short* wb2 = (unsigned short*)out1;
    float* partial = out1 + WB2_FLOATS;

    conv_kernel<<<128, 256, 0, stream>>>(w, wb2);
    comp_kernel<<<768, 256, 0, stream>>>(x, y, wb2, partial);
    reduce_kernel<<<2304, 256, 0, stream>>>(as, partial, out2);
    stream_kernel<<<4096, 256, 0, stream>>>(x, y, out1);
    finish_kernel<<<1408, 256, 0, stream>>>(x, y, out1);
}

// Round 10
// 104.105 us; speedup vs baseline: 2.5295x; 1.0063x over previous
//
#include <hip/hip_runtime.h>
#include <stdint.h>

typedef __attribute__((ext_vector_type(8))) short bf16x8;
typedef __attribute__((ext_vector_type(4))) float f32x4;

static constexpr int O1_ELEMS    = 512*3*3*128*128;   // 75497472 floats
static constexpr int WB2_FLOATS  = 1048576;           // 4 MB bf16 wb2[a][k][b]
static constexpr int P_FLOATS    = 512*9*128;         // 589824 per partial slice
static constexpr int NSEG        = 8;                 // a-split
static constexpr size_t SCRATCH_BYTES = (size_t)WB2_FLOATS*4 + (size_t)NSEG*P_FLOATS*4; // 23068672
static constexpr int SKIP_FLOATS = WB2_FLOATS + NSEG*P_FLOATS;  // 5767168 (fallback)
static constexpr int SKIP4       = SKIP_FLOATS / 4;   // 1441792 float4
static constexpr int TOTAL4      = O1_ELEMS / 4;      // 18874368
static constexpr int NSTREAM     = 4096;

__device__ inline unsigned short f32_to_bf16(float f) {
    union { float f; uint32_t u; } v; v.f = f;
    uint32_t r = v.u + 0x7FFF + ((v.u >> 16) & 1);    // RNE
    return (unsigned short)(r >> 16);
}

__device__ inline bf16x8 bf16x8_from_f32(const float* p) {
    float4 v0 = *(const float4*)p;
    float4 v1 = *(const float4*)(p + 4);
    union { bf16x8 v; unsigned short s[8]; } u;
    u.s[0] = f32_to_bf16(v0.x); u.s[1] = f32_to_bf16(v0.y);
    u.s[2] = f32_to_bf16(v0.z); u.s[3] = f32_to_bf16(v0.w);
    u.s[4] = f32_to_bf16(v1.x); u.s[5] = f32_to_bf16(v1.y);
    u.s[6] = f32_to_bf16(v1.z); u.s[7] = f32_to_bf16(v1.w);
    return u.v;
}

// out1[n,i,j,a,b] = x[n,i,a]*y[n,j,b], flat float4 range [lo, hi)
__device__ inline void out1_range(int lo, int hi, int stride, int start,
                                  const float* __restrict__ x,
                                  const float4* __restrict__ y4,
                                  float4* __restrict__ o4) {
    for (int idx = lo + start; idx < hi; idx += stride) {
        int n   = idx / 36864;
        int rem = idx - n * 36864;
        int ij  = rem >> 12;
        int r2  = rem & 4095;
        int aa  = r2 >> 5;
        int b4  = r2 & 31;
        int i = ij / 3, j = ij - 3 * i;
        float  xs1 = x[(n * 3 + i) * 128 + aa];
        float4 yv  = y4[(n * 3 + j) * 32 + b4];
        float4 r; r.x = xs1 * yv.x; r.y = xs1 * yv.y; r.z = xs1 * yv.z; r.w = xs1 * yv.w;
        o4[idx] = r;
    }
}

// ---- conv: wb2[a][k][b] = bf16(w[a][b][k]) ----
__global__ __launch_bounds__(256) void conv_kernel(const float* __restrict__ w,
                                                   unsigned short* __restrict__ wb2) {
    __shared__ unsigned short lt[128][132];
    const int a = blockIdx.x;
    const int t = threadIdx.x;
    const float4* src = (const float4*)(w + (size_t)a * 16384);
    #pragma unroll
    for (int it = 0; it < 16; ++it) {                  // 4096 float4 = 128x128 f32
        int fidx = it * 256 + t;
        float4 v = src[fidx];
        int b = fidx >> 5, k4 = fidx & 31;
        unsigned short* d = &lt[b][k4 * 4];
        d[0] = f32_to_bf16(v.x); d[1] = f32_to_bf16(v.y);
        d[2] = f32_to_bf16(v.z); d[3] = f32_to_bf16(v.w);
    }
    __syncthreads();
    const int k = t >> 1, bh = t & 1;
    uint4* dst = (uint4*)(wb2 + (size_t)a * 16384 + (size_t)k * 128 + bh * 64);
    #pragma unroll
    for (int i8 = 0; i8 < 8; ++i8) {
        uint32_t pk[4];
        #pragma unroll
        for (int q = 0; q < 4; ++q) {
            uint32_t lo = lt[bh * 64 + i8 * 8 + q * 2][k];
            uint32_t hi = lt[bh * 64 + i8 * 8 + q * 2 + 1][k];
            pk[q] = lo | (hi << 16);
        }
        uint4 vv = {pk[0], pk[1], pk[2], pk[3]};
        dst[i8] = vv;
    }
}

// ---- comp: partial[aseg][m,k] = sum_{a in seg} x[n,i,a] * t_a[m,k] ----
// grid 768 = 48 mt x 2 kt x 8 aseg, 256 threads
__global__ __launch_bounds__(256) void comp_kernel(const float* __restrict__ x,
                                                   const float* __restrict__ y,
                                                   const unsigned short* __restrict__ wb2,
                                                   float* __restrict__ partial) {
    __shared__ float xsh[16][3][32];       // [ac][i][m']  6 KB
    const int bid  = blockIdx.x;
    const int aseg = bid & 7;
    const int kt   = (bid >> 3) & 1;
    const int mt   = bid >> 4;             // 0..47
    const int tid  = threadIdx.x;
    const int l    = tid & 63;
    const int wv   = tid >> 6;             // wave -> k-cols [wv*16, +16) of kt half
    const int l15  = l & 15, lg = l >> 4;

    bf16x8 afrag[2][4];
    #pragma unroll
    for (int Mt = 0; Mt < 2; ++Mt)
        #pragma unroll
        for (int ks = 0; ks < 4; ++ks)
            afrag[Mt][ks] = bf16x8_from_f32(
                y + (size_t)(mt * 32 + Mt * 16 + l15) * 128 + ks * 32 + lg * 8);

    #pragma unroll
    for (int p = 0; p < 6; ++p) {
        int e = tid + p * 256;
        int ac = e / 96, r = e - ac * 96, i = r >> 5, mm = r & 31;
        int n = (mt * 32 + mm) / 3;
        xsh[ac][i][mm] = x[n * 384 + i * 128 + aseg * 16 + ac];
    }
    __syncthreads();

    float acc2[3][2][4] = {};
    const unsigned short* wbase =
        wb2 + (size_t)(kt * 64 + wv * 16 + l15) * 128 + lg * 8;

    #pragma unroll 4
    for (int ac = 0; ac < 16; ++ac) {
        const int a = aseg * 16 + ac;
        const unsigned short* wp = wbase + (size_t)a * 16384;
        bf16x8 bf0 = *(const bf16x8*)(wp);
        bf16x8 bf1 = *(const bf16x8*)(wp + 32);
        bf16x8 bf2 = *(const bf16x8*)(wp + 64);
        bf16x8 bf3 = *(const bf16x8*)(wp + 96);

        f32x4 t0 = {0.f, 0.f, 0.f, 0.f}, t1 = {0.f, 0.f, 0.f, 0.f};
        t0 = __builtin_amdgcn_mfma_f32_16x16x32_bf16(afrag[0][0], bf0, t0, 0, 0, 0);
        t1 = __builtin_amdgcn_mfma_f32_16x16x32_bf16(afrag[1][0], bf0, t1, 0, 0, 0);
        t0 = __builtin_amdgcn_mfma_f32_16x16x32_bf16(afrag[0][1], bf1, t0, 0, 0, 0);
        t1 = __builtin_amdgcn_mfma_f32_16x16x32_bf16(afrag[1][1], bf1, t1, 0, 0, 0);
        t0 = __builtin_amdgcn_mfma_f32_16x16x32_bf16(afrag[0][2], bf2, t0, 0, 0, 0);
        t1 = __builtin_amdgcn_mfma_f32_16x16x32_bf16(afrag[1][2], bf2, t1, 0, 0, 0);
        t0 = __builtin_amdgcn_mfma_f32_16x16x32_bf16(afrag[0][3], bf3, t0, 0, 0, 0);
        t1 = __builtin_amdgcn_mfma_f32_16x16x32_bf16(afrag[1][3], bf3, t1, 0, 0, 0);

        #pragma unroll
        for (int i = 0; i < 3; ++i) {
            float4 xv0 = *(const float4*)&xsh[ac][i][lg * 4];
            float4 xv1 = *(const float4*)&xsh[ac][i][16 + lg * 4];
            acc2[i][0][0] += xv0.x * t0[0]; acc2[i][0][1] += xv0.y * t0[1];
            acc2[i][0][2] += xv0.z * t0[2]; acc2[i][0][3] += xv0.w * t0[3];
            acc2[i][1][0] += xv1.x * t1[0]; acc2[i][1][1] += xv1.y * t1[1];
            acc2[i][1][2] += xv1.z * t1[2]; acc2[i][1][3] += xv1.w * t1[3];
        }
    }

    float* pp = partial + (size_t)aseg * P_FLOATS;
    const int kcol = kt * 64 + wv * 16 + l15;
    #pragma unroll
    for (int i = 0; i < 3; ++i)
        #pragma unroll
        for (int Mt = 0; Mt < 2; ++Mt)
            #pragma unroll
            for (int r = 0; r < 4; ++r) {
                int m = mt * 32 + Mt * 16 + lg * 4 + r;
                int n = m / 3, j = m - 3 * n;
                pp[((size_t)(n * 3 + i) * 3 + j) * 128 + kcol] = acc2[i][Mt][r];
            }
}

// ---- streamreduce: blocks 0..2303 also reduce partials -> out2, then all
//      blocks stream out1 [lo4, TOTAL4) ----
__global__ __launch_bounds__(256) void streamreduce_kernel(
        const float* __restrict__ x, const float* __restrict__ y,
        const float* __restrict__ a_s, const float* __restrict__ partial,
        float* __restrict__ out1, float* __restrict__ out2, int lo4) {
    const int bid = (int)blockIdx.x;
    if (bid < 2304) {
        const int e = bid * 256 + (int)threadIdx.x;    // 2304*256 = P_FLOATS exact
        float s = 0.f;
        #pragma unroll
        for (int sg = 0; sg < NSEG; ++sg) s += partial[(size_t)sg * P_FLOATS + e];
        out2[e] = 0.75f * a_s[0] * s;
    }
    out1_range(lo4, TOTAL4, NSTREAM * 256,
               bid * 256 + (int)threadIdx.x,
               x, (const float4*)y, (float4*)out1);
}

// ---- finish (fallback only): rewrite scratch head [0, SKIP4) ----
__global__ __launch_bounds__(256) void finish_kernel(const float* __restrict__ x,
                                                     const float* __restrict__ y,
                                                     float* __restrict__ out1) {
    out1_range(0, SKIP4, 1408 * 256,
               (int)blockIdx.x * 256 + (int)threadIdx.x,
               x, (const float4*)y, (float4*)out1);
}

extern "C" void kernel_launch(void* const* d_in, const int* in_sizes, int n_in,
                              void* d_out, int out_size, void* d_ws, size_t ws_size,
                              hipStream_t stream) {
    const float* w  = (const float*)d_in[0];
    const float* as = (const float*)d_in[1];
    const float* x  = (const float*)d_in[2];
    const float* y  = (const float*)d_in[3];
    float* out1 = (float*)d_out;
    float* out2 = out1 + O1_ELEMS;

    const bool have_ws = (ws_size >= SCRATCH_BYTES);
    unsigned short* wb2;
    float* partial;
    int lo4;
    if (have_ws) {               // scratch in d_ws: one clean full-range stream
        wb2 = (unsigned short*)d_ws;
        partial = (float*)d_ws + WB2_FLOATS;
        lo4 = 0;
    } else {                     // scratch at out1 head, rewritten by finish
        wb2 = (unsigned short*)out1;
        partial = out1 + WB2_FLOATS;
        lo4 = SKIP4;
    }

    conv_kernel<<<128, 256, 0, stream>>>(w, wb2);
    comp_kernel<<<768, 256, 0, stream>>>(x, y, wb2, partial);
    streamreduce_kernel<<<NSTREAM, 256, 0, stream>>>(x, y, as, partial, out1, out2, lo4);
    if (!have_ws)
        finish_kernel<<<1408, 256, 0, stream>>>(x, y, out1);
}